// Round 13
// baseline (65.821 us; speedup 1.0000x reference)
//
#include <hip/hip_runtime.h>

// ParallelLinear: out[b,t,o] = sum_i x[b,t,i] * W[t,o,i] + bias[t,o]
// B=512, T=1024, ISIZE=OSIZE=64, fp32 in/out.
//
// v13 = v12 (64.4us: persistent per-t, non-draining lgkm barriers) +
//  (1) W-frags hoisted from LDS into registers ONCE per block: per-chunk
//      DS ops drop 24 -> 8 b128 (W was re-read from LDS 8x redundantly).
//      LDS-sourced, statically-indexed -> immune to the R4/R9 global-
//      demotion trap. 64 VGPR; __launch_bounds__(256,3) caps at 170.
//  (2) Double-buffered X planes -> ONE lgkm-only barrier per chunk:
//      stage(c+1) overlaps compute(c); max skew one phase, buffers
//      alternate -> race-free. pf(c+2) issued mid-iter (~1.5 chunks of
//      latency cover, vmcnt never drained in the loop).
// LDS = 2x(Xh+Xl) 32KB + Wh/Wl 16KB = 48KB -> 3 blocks/CU, 12 waves.
// Numerics: the 7x-verified 3-term bf16 hi/lo split (absmax 0.0156).

#define T_DIM 1024
#define B_DIM 512
#define KSZ 64
#define OSZ 64
#define ROWS 64
#define NCH (B_DIM / ROWS)   // 8

typedef __attribute__((ext_vector_type(8))) short short8;   // 8 bf16
typedef __attribute__((ext_vector_type(4))) float f32x4;

static __device__ __forceinline__ unsigned short f2bf(float f) {
    unsigned u = __float_as_uint(f);
    u += 0x7FFFu + ((u >> 16) & 1u);          // RNE
    return (unsigned short)(u >> 16);
}
static __device__ __forceinline__ float bf2f(unsigned short h) {
    return __uint_as_float((unsigned)h << 16);
}

// lgkm-only barrier: LDS ordering preserved, global loads stay in flight.
#define LGKM_BARRIER() do {                                   \
    asm volatile("s_waitcnt lgkmcnt(0)" ::: "memory");        \
    __builtin_amdgcn_s_barrier();                             \
} while (0)

__global__ __launch_bounds__(256, 3) void pl_kernel(
    const float* __restrict__ x,
    const float* __restrict__ W,
    const float* __restrict__ bias,
    float* __restrict__ out)
{
    __shared__ short Xh[2][ROWS * KSZ];   // 2 x 8 KB (double-buffered hi plane)
    __shared__ short Xl[2][ROWS * KSZ];   // 2 x 8 KB
    __shared__ short Wh[OSZ * KSZ];       // 8 KB
    __shared__ short Wl[OSZ * KSZ];       // 8 KB    -> 48 KB total, 3 blocks/CU

    const int t   = blockIdx.x;           // 0..1023, persistent per t
    const int tid = threadIdx.x;

    // staging coords (verified): thread = (row sr, 16-float chunk kc)
    const int sr = tid >> 2;              // 0..63
    const int kc = tid & 3;               // 0..3
    // compute coords (verified)
    const int w  = tid >> 6;              // wave 0..3
    const int l  = tid & 63;
    const int n  = l & 15;
    const int kq = l >> 4;                // 0..3

    const size_t cstep = (size_t)ROWS * T_DIM * KSZ;   // floats per 64-row chunk
    const float* xp0 = x + ((size_t)sr * T_DIM + t) * KSZ + 16 * kc;

    // ---- prefetch chunk 0 (in flight under W staging) ----
    float4 pf0 = *(const float4*)(xp0);
    float4 pf1 = *(const float4*)(xp0 + 4);
    float4 pf2 = *(const float4*)(xp0 + 8);
    float4 pf3 = *(const float4*)(xp0 + 12);

    const int p0 = (((2 * kc)     ^ (sr & 7)) << 3);
    const int p1 = (((2 * kc + 1) ^ (sr & 7)) << 3);

    // ---- stage W[t] planes once (verified swizzle, conflict-free) ----
    {
        const float* wp = W + (size_t)t * (OSZ * KSZ) + (size_t)sr * KSZ + 16 * kc;
        float4 g0 = *(const float4*)(wp);
        float4 g1 = *(const float4*)(wp + 4);
        float4 g2 = *(const float4*)(wp + 8);
        float4 g3 = *(const float4*)(wp + 12);
        float a[8]  = {g0.x, g0.y, g0.z, g0.w, g1.x, g1.y, g1.z, g1.w};
        float b2[8] = {g2.x, g2.y, g2.z, g2.w, g3.x, g3.y, g3.z, g3.w};
        short8 h0, l0, h1, l1;
        #pragma unroll
        for (int j = 0; j < 8; ++j) {
            unsigned short hh = f2bf(a[j]);
            h0[j] = (short)hh; l0[j] = (short)f2bf(a[j] - bf2f(hh));
            unsigned short h2 = f2bf(b2[j]);
            h1[j] = (short)h2; l1[j] = (short)f2bf(b2[j] - bf2f(h2));
        }
        *(short8*)&Wh[sr * KSZ + p0] = h0;
        *(short8*)&Wl[sr * KSZ + p0] = l0;
        *(short8*)&Wh[sr * KSZ + p1] = h1;
        *(short8*)&Wl[sr * KSZ + p1] = l1;
    }

    LGKM_BARRIER();

    // ---- hoist W-frags into registers (16 b128 reads, once per block) ----
    // B-frag layout (verified): lane holds W[o=16ct+n][k=(ks*4+kq)*8+j]
    short8 wfh[4][2], wfl[4][2];
    #pragma unroll
    for (int ct = 0; ct < 4; ++ct) {
        const int brow = 16 * ct + n;
        #pragma unroll
        for (int ks = 0; ks < 2; ++ks) {
            const int pos = ((ks * 4 + kq) ^ (brow & 7)) << 3;
            wfh[ct][ks] = *(const short8*)&Wh[brow * KSZ + pos];
            wfl[ct][ks] = *(const short8*)&Wl[brow * KSZ + pos];
        }
    }

    // hoist bias
    float bv[4];
    #pragma unroll
    for (int ct = 0; ct < 4; ++ct)
        bv[ct] = bias[(size_t)t * OSZ + 16 * ct + n];

    #pragma unroll 2
    for (int c = 0; c < NCH; ++c) {
        short* xh = &Xh[c & 1][0];
        short* xl = &Xl[c & 1][0];

        // ---- stage chunk c into buf[c&1] (overlaps other waves' compute(c-1)) ----
        {
            float a[8]  = {pf0.x, pf0.y, pf0.z, pf0.w, pf1.x, pf1.y, pf1.z, pf1.w};
            float b2[8] = {pf2.x, pf2.y, pf2.z, pf2.w, pf3.x, pf3.y, pf3.z, pf3.w};
            short8 h0, l0, h1, l1;
            #pragma unroll
            for (int j = 0; j < 8; ++j) {
                unsigned short hh = f2bf(a[j]);
                h0[j] = (short)hh; l0[j] = (short)f2bf(a[j] - bf2f(hh));
                unsigned short h2 = f2bf(b2[j]);
                h1[j] = (short)h2; l1[j] = (short)f2bf(b2[j] - bf2f(h2));
            }
            *(short8*)&xh[sr * KSZ + p0] = h0;
            *(short8*)&xl[sr * KSZ + p0] = l0;
            *(short8*)&xh[sr * KSZ + p1] = h1;
            *(short8*)&xl[sr * KSZ + p1] = l1;
        }

        // ---- issue prefetch for chunk c+1 (stays in flight across barrier) ----
        if (c + 1 < NCH) {
            const float* xp = xp0 + (size_t)(c + 1) * cstep;
            pf0 = *(const float4*)(xp);
            pf1 = *(const float4*)(xp + 4);
            pf2 = *(const float4*)(xp + 8);
            pf3 = *(const float4*)(xp + 12);
        }

        LGKM_BARRIER();   // buf[c&1] visible; vmcnt untouched (single barrier/chunk)

        // ---- compute chunk c: A-frags (4 ds_read) + 24 MFMA, W from regs ----
        const int arow = 16 * w + n;
        short8 ah[2], al[2];
        #pragma unroll
        for (int ks = 0; ks < 2; ++ks) {
            const int pos = ((ks * 4 + kq) ^ (arow & 7)) << 3;
            ah[ks] = *(const short8*)&xh[arow * KSZ + pos];
            al[ks] = *(const short8*)&xl[arow * KSZ + pos];
        }

        f32x4 acc[4] = {};
        #pragma unroll
        for (int ct = 0; ct < 4; ++ct) {
            #pragma unroll
            for (int ks = 0; ks < 2; ++ks) {
                acc[ct] = __builtin_amdgcn_mfma_f32_16x16x32_bf16(ah[ks], wfh[ct][ks], acc[ct], 0, 0, 0);
                acc[ct] = __builtin_amdgcn_mfma_f32_16x16x32_bf16(al[ks], wfh[ct][ks], acc[ct], 0, 0, 0);
                acc[ct] = __builtin_amdgcn_mfma_f32_16x16x32_bf16(ah[ks], wfl[ct][ks], acc[ct], 0, 0, 0);
            }
        }

        // ---- epilogue (verified C/D map: col = n, row = 4*kq + j) ----
        const int row0 = c * ROWS;
        #pragma unroll
        for (int ct = 0; ct < 4; ++ct) {
            #pragma unroll
            for (int j = 0; j < 4; ++j) {
                const size_t b = (size_t)row0 + 16 * w + 4 * kq + j;
                out[(b * T_DIM + t) * OSZ + 16 * ct + n] = acc[ct][j] + bv[ct];
            }
        }
    }
}

extern "C" void kernel_launch(void* const* d_in, const int* in_sizes, int n_in,
                              void* d_out, int out_size, void* d_ws, size_t ws_size,
                              hipStream_t stream) {
    const float* x    = (const float*)d_in[0];
    const float* W    = (const float*)d_in[1];
    const float* bias = (const float*)d_in[2];
    float* out        = (float*)d_out;

    dim3 grid(T_DIM);                    // 1024 persistent blocks, 3/CU
    dim3 block(256);
    pl_kernel<<<grid, block, 0, stream>>>(x, W, bias, out);
}